// Round 13
// baseline (189.810 us; speedup 1.0000x reference)
//
#include <hip/hip_runtime.h>
#include <math.h>

#define DEV __device__ __forceinline__

constexpr int Bb   = 2;
constexpr int Seq  = 1024;
constexpr int Dim  = 1024;
constexpr int Hh   = 8;
constexpr int Dh   = 64;
constexpr int Di   = 512;
constexpr int BN   = Bb * Seq;       // 2048
constexpr int NSEQ = Bb * Hh;        // 16
constexpr int CHUNK = 32;            // chunks per sequence
constexpr int CLEN  = Seq / CHUNK;   // 32
constexpr float EPSV = 1.1920929e-07f;
constexpr int NT2  = 8;              // conv timesteps per block
constexpr int KSPL = 8;              // gate GEMM K-splits

typedef _Float16 half8 __attribute__((ext_vector_type(8)));
typedef float    f32x4 __attribute__((ext_vector_type(4)));

DEV float bf2f(unsigned short u) {
  union { unsigned int i; float f; } x; x.i = ((unsigned int)u) << 16; return x.f;
}
DEV unsigned short f2bf(float f) {
  union { float f; unsigned int i; } x; x.f = f;
  unsigned int r = x.i + 0x7fffu + ((x.i >> 16) & 1u);
  return (unsigned short)(r >> 16);
}
// flag: 1 -> fp32, 0 -> bf16
DEV float ldin(const void* p, int f32, size_t i) {
  if (f32) return ((const float*)p)[i];
  return bf2f(((const unsigned short*)p)[i]);
}
DEV void ld4(const void* p, int f32, size_t i, float* dst) {
  if (f32) {
    float4 u = *(const float4*)((const float*)p + i);
    dst[0] = u.x; dst[1] = u.y; dst[2] = u.z; dst[3] = u.w;
  } else {
    ushort4 u = *(const ushort4*)((const unsigned short*)p + i);
    dst[0] = bf2f(u.x); dst[1] = bf2f(u.y); dst[2] = bf2f(u.z); dst[3] = bf2f(u.w);
  }
}
// decode 16 contiguous values to f16 (branch hoisted, vectorized)
DEV void ldc16(const void* p, int f32, size_t base, _Float16* dst) {
  if (f32) {
#pragma unroll
    for (int q = 0; q < 4; ++q) {
      float4 u = *(const float4*)((const float*)p + base + q * 4);
      dst[q * 4 + 0] = (_Float16)u.x; dst[q * 4 + 1] = (_Float16)u.y;
      dst[q * 4 + 2] = (_Float16)u.z; dst[q * 4 + 3] = (_Float16)u.w;
    }
  } else {
#pragma unroll
    for (int q = 0; q < 2; ++q) {
      ushort4 u0 = *(const ushort4*)((const unsigned short*)p + base + q * 8);
      ushort4 u1 = *(const ushort4*)((const unsigned short*)p + base + q * 8 + 4);
      dst[q * 8 + 0] = (_Float16)bf2f(u0.x); dst[q * 8 + 1] = (_Float16)bf2f(u0.y);
      dst[q * 8 + 2] = (_Float16)bf2f(u0.z); dst[q * 8 + 3] = (_Float16)bf2f(u0.w);
      dst[q * 8 + 4] = (_Float16)bf2f(u1.x); dst[q * 8 + 5] = (_Float16)bf2f(u1.y);
      dst[q * 8 + 6] = (_Float16)bf2f(u1.z); dst[q * 8 + 7] = (_Float16)bf2f(u1.w);
    }
  }
}
// per-wave sample vote: works for any full wave; sample index = 2*tid
DEV int sniff_vote(const void* p, int n, int tid) {
  int j = 2 * tid, valid = 0, bad = 0;
  if (j < n) {
    valid = 1;
    float v = bf2f(((const unsigned short*)p)[j]);
    float a = fabsf(v);
    if (!(a >= 1e-12f && a <= 1e4f)) bad = 1;
  }
#pragma unroll
  for (int m = 1; m < 64; m <<= 1) { valid += __shfl_xor(valid, m); bad += __shfl_xor(bad, m); }
  return (2 * bad > valid) ? 1 : 0;
}

struct InPtrs { const void* p[17]; int n[17]; };

// ---------------------------------------------------------------------------
// K0: MEGA prep+rmsconv. Block roles:
//   [0,256)     : fused RMSNorm+conv (self-sniff x/w_rms/conv; tb=blk>>1, b=blk&1)
//   [256,1280)  : transpose+convert wq/wk/wv/wo -> f16 [N][K]
//   [1280,1344) : gate weights -> WgT[64][1024]
//   1344        : flags[17] + gammas + gate biases
// ---------------------------------------------------------------------------
__global__ __launch_bounds__(256) void k_prep_rmsconv(
    InPtrs ip,
    int* __restrict__ flags,
    _Float16* __restrict__ wqT, _Float16* __restrict__ wkT,
    _Float16* __restrict__ wvT, _Float16* __restrict__ woT,
    _Float16* __restrict__ WgT,
    float* __restrict__ gqf, float* __restrict__ gkf, float* __restrict__ gbf,
    _Float16* __restrict__ xaf,
    _Float16* __restrict__ qc, _Float16* __restrict__ kc,
    _Float16* __restrict__ vc)
{
  constexpr int NR = NT2 + 3;   // 11 halo rows
  __shared__ _Float16 xas[NR][Dim];
  __shared__ float tile[64][65];
  __shared__ int sfl[8];

  int blk = blockIdx.x;
  int tid = threadIdx.x, lane = tid & 63, wv = tid >> 6;

  if (blk < 256) {
    // ---- fused RMSNorm + conv ----
    int tb = blk >> 1, b = blk & 1;
    int t0 = tb * NT2;
    // per-wave self-sniff (each wave gets its own consistent vote)
    int fx = sniff_vote(ip.p[0], ip.n[0], tid);
    int fw = sniff_vote(ip.p[1], ip.n[1], tid);
    int e0 = lane * 16;

    float wr[16];
#pragma unroll
    for (int q = 0; q < 4; ++q) ld4(ip.p[1], fw, e0 + q * 4, &wr[q * 4]);

    for (int rr = wv; rr < NR; rr += 4) {
      int r = t0 - 2 + rr;
      float xv[16];
      bool inr = (r >= 0 && r < Seq);
      if (inr) {
        size_t rb = (size_t)(b * Seq + r) * Dim + e0;
#pragma unroll
        for (int q = 0; q < 4; ++q) ld4(ip.p[0], fx, rb + q * 4, &xv[q * 4]);
      } else {
#pragma unroll
        for (int j = 0; j < 16; ++j) xv[j] = 0.f;
      }
      float ss = 0.f;
#pragma unroll
      for (int j = 0; j < 16; ++j) ss = fmaf(xv[j], xv[j], ss);
#pragma unroll
      for (int m = 1; m < 64; m <<= 1) ss += __shfl_xor(ss, m);
      float scale = rsqrtf(ss * (1.0f / Dim) + EPSV);

      _Float16 o[16];
#pragma unroll
      for (int j = 0; j < 16; ++j) o[j] = (_Float16)(xv[j] * scale * wr[j]);
      *(uint4*)&xas[rr][e0]     = *(uint4*)&o[0];
      *(uint4*)&xas[rr][e0 + 8] = *(uint4*)&o[8];
      if (inr && r >= t0 && r < t0 + NT2) {
        size_t ob = (size_t)(b * Seq + r) * Dim + e0;
        *(uint4*)&xaf[ob]     = *(uint4*)&o[0];
        *(uint4*)&xaf[ob + 8] = *(uint4*)&o[8];
      }
    }

    int f6 = sniff_vote(ip.p[6], ip.n[6], tid);
    int f7 = sniff_vote(ip.p[7], ip.n[7], tid);
    int f8 = sniff_vote(ip.p[8], ip.n[8], tid);
    int c0 = tid * 4;
    _Float16 lwq[16], lwk[16], lwv[16];
    ldc16(ip.p[6], f6, (size_t)c0 * 4, lwq);
    ldc16(ip.p[7], f7, (size_t)c0 * 4, lwk);
    ldc16(ip.p[8], f8, (size_t)c0 * 4, lwv);
    __syncthreads();

#pragma unroll
    for (int tt = 0; tt < NT2; ++tt) {
      float rv[4][4];
#pragma unroll
      for (int k = 0; k < 4; ++k) {
        _Float16 hx[4];
        *(ushort4*)hx = *(const ushort4*)&xas[tt + k][c0];
#pragma unroll
        for (int j = 0; j < 4; ++j) rv[k][j] = (float)hx[j];
      }
      _Float16 tq[4], tk[4], tv[4];
#pragma unroll
      for (int j = 0; j < 4; ++j) {
        float aq = rv[0][j] * (float)lwq[j * 4 + 0] + rv[1][j] * (float)lwq[j * 4 + 1]
                 + rv[2][j] * (float)lwq[j * 4 + 2] + rv[3][j] * (float)lwq[j * 4 + 3];
        float ak = rv[0][j] * (float)lwk[j * 4 + 0] + rv[1][j] * (float)lwk[j * 4 + 1]
                 + rv[2][j] * (float)lwk[j * 4 + 2] + rv[3][j] * (float)lwk[j * 4 + 3];
        float av = rv[0][j] * (float)lwv[j * 4 + 0] + rv[1][j] * (float)lwv[j * 4 + 1]
                 + rv[2][j] * (float)lwv[j * 4 + 2] + rv[3][j] * (float)lwv[j * 4 + 3];
        tq[j] = (_Float16)aq; tk[j] = (_Float16)ak; tv[j] = (_Float16)av;
      }
      size_t o = ((size_t)(b * Seq + t0 + tt)) * Dim + c0;
      *(ushort4*)&qc[o] = *(ushort4*)tq;
      *(ushort4*)&kc[o] = *(ushort4*)tk;
      *(ushort4*)&vc[o] = *(ushort4*)tv;
    }
  } else if (blk < 1280) {
    // ---- weight transpose ----
    int bb = blk - 256;
    int z = bb >> 8, bx = bb & 15, by = (bb >> 4) & 15;
    int idx = (z == 0) ? 2 : ((z == 1) ? 3 : ((z == 2) ? 4 : 5));
    const void* src = ip.p[idx];
    _Float16* dst   = (z == 0) ? wqT : ((z == 1) ? wkT : ((z == 2) ? wvT : woT));
    int Kd = (z < 3) ? Dim : Di;
    int Nn = (z < 3) ? Di : Dim;
    int n0 = bx * 64, k0 = by * 64;
    if (n0 >= Nn || k0 >= Kd) return;

    if (tid < 64) { int f = sniff_vote(src, ip.n[idx], tid); if (tid == 0) sfl[0] = f; }
    __syncthreads();
    int f = sfl[0];

    int r = tid >> 4, c4 = (tid & 15) * 4;
#pragma unroll
    for (int rr = 0; rr < 4; ++rr) {
      int k = rr * 16 + r;
      ld4(src, f, (size_t)(k0 + k) * Nn + n0 + c4, &tile[k][c4]);
    }
    __syncthreads();
#pragma unroll
    for (int rr = 0; rr < 4; ++rr) {
      int n = rr * 16 + r;
      _Float16 o4[4];
#pragma unroll
      for (int j = 0; j < 4; ++j) o4[j] = (_Float16)tile[c4 + j][n];
      *(ushort4*)&dst[(size_t)(n0 + n) * Kd + k0 + c4] = *(ushort4*)o4;
    }
  } else if (blk < 1344) {
    int row = blk - 1280;   // 0..63
    if (row < 24) {
      int g = row >> 3, h = row & 7;
      int idx = (g == 0) ? 11 : ((g == 1) ? 13 : 15);
      const void* W = ip.p[idx];
      if (tid < 64) { int f = sniff_vote(W, ip.n[idx], tid); if (tid == 0) sfl[0] = f; }
      __syncthreads();
      int f = sfl[0];
#pragma unroll
      for (int it = 0; it < 4; ++it) {
        int d = it * 256 + tid;
        WgT[(size_t)row * Dim + d] = (_Float16)ldin(W, f, (size_t)d * Hh + h);
      }
    } else {
#pragma unroll
      for (int it = 0; it < 4; ++it)
        WgT[(size_t)row * Dim + it * 256 + tid] = (_Float16)0.f;
    }
  } else {
    __shared__ int allf[17];
    for (int ii = 0; ii < 17; ++ii) {
      if (tid < 64) {
        int f = sniff_vote(ip.p[ii], ip.n[ii], tid);
        if (tid == 0) { flags[ii] = f; allf[ii] = f; }
      }
    }
    __syncthreads();
    int f9 = allf[9], f10 = allf[10];
    for (int i = tid; i < Di; i += 256) {
      gqf[i] = ldin(ip.p[9], f9, i);
      gkf[i] = ldin(ip.p[10], f10, i);
    }
    if (tid < 24) {
      int g = tid >> 3, h = tid & 7;
      int idx = (g == 0) ? 12 : ((g == 1) ? 14 : 16);
      gbf[tid] = ldin(ip.p[idx], allf[idx], h);
    }
  }
}

// ---------------------------------------------------------------------------
// K1: fused mid kernel. Blocks [0,384): QKV MFMA GEMM (128x64 tiles).
// Blocks [384,640): gate GEMM K-split partials.
// ---------------------------------------------------------------------------
__global__ __launch_bounds__(256) void k_mid(
    const _Float16* __restrict__ qc, const _Float16* __restrict__ kc,
    const _Float16* __restrict__ vc,
    const _Float16* __restrict__ wqT, const _Float16* __restrict__ wkT,
    const _Float16* __restrict__ wvT,
    const _Float16* __restrict__ xaf, const _Float16* __restrict__ WgT,
    _Float16* __restrict__ qpre, _Float16* __restrict__ kpre,
    _Float16* __restrict__ vpre,
    float* __restrict__ gpart)
{
  __shared__ __align__(16) _Float16 As[128][40];
  __shared__ __align__(16) _Float16 Bs[64][40];

  int blk = blockIdx.x;
  int tid = threadIdx.x, lane = tid & 63, wv = tid >> 6;
  int mrow = lane & 15, quad = lane >> 4;

  if (blk < 384) {
    int z = blk / 128, rem = blk - z * 128;
    int by = rem >> 3, bx = rem & 7;
    const _Float16* A  = (z == 0) ? qc : ((z == 1) ? kc : vc);
    const _Float16* Bt = (z == 0) ? wqT : ((z == 1) ? wkT : wvT);
    _Float16* C        = (z == 0) ? qpre : ((z == 1) ? kpre : vpre);
    int n0 = bx * 64, m0 = by * 128;
    int wm = wv * 32;
    int ar0 = tid >> 2, ac0 = (tid & 3) * 8;
    int ar1 = (tid + 256) >> 2;

    f32x4 acc[2][4];
#pragma unroll
    for (int mi = 0; mi < 2; ++mi)
#pragma unroll
      for (int ni = 0; ni < 4; ++ni) acc[mi][ni] = (f32x4){0.f, 0.f, 0.f, 0.f};

    for (int kt = 0; kt < Dim; kt += 32) {
      __syncthreads();
      *(uint4*)&As[ar0][ac0] = *(const uint4*)&A[(size_t)(m0 + ar0) * Dim + kt + ac0];
      *(uint4*)&As[ar1][ac0] = *(const uint4*)&A[(size_t)(m0 + ar1) * Dim + kt + ac0];
      *(uint4*)&Bs[ar0][ac0] = *(const uint4*)&Bt[(size_t)(n0 + ar0) * Dim + kt + ac0];
      __syncthreads();

      half8 bfr[4];
#pragma unroll
      for (int ni = 0; ni < 4; ++ni)
        bfr[ni] = *(const half8*)&Bs[ni * 16 + mrow][quad * 8];
#pragma unroll
      for (int mi = 0; mi < 2; ++mi) {
        half8 afr = *(const half8*)&As[wm + mi * 16 + mrow][quad * 8];
#pragma unroll
        for (int ni = 0; ni < 4; ++ni)
          acc[mi][ni] = __builtin_amdgcn_mfma_f32_16x16x32_f16(afr, bfr[ni], acc[mi][ni], 0, 0, 0);
      }
    }

#pragma unroll
    for (int mi = 0; mi < 2; ++mi) {
#pragma unroll
      for (int ni = 0; ni < 4; ++ni) {
        int col = n0 + ni * 16 + mrow;
#pragma unroll
        for (int r2 = 0; r2 < 4; ++r2) {
          int row = m0 + wm + mi * 16 + quad * 4 + r2;
          C[(size_t)row * Di + col] = (_Float16)acc[mi][ni][r2];
        }
      }
    }
  } else {
    int g = blk - 384;
    int m0 = (g & 31) * 64, ks = g >> 5;
    int srow = tid >> 2, scol = (tid & 3) * 8;
    int kbase = ks * (Dim / KSPL);

    f32x4 acc[4];
#pragma unroll
    for (int mi = 0; mi < 4; ++mi) acc[mi] = (f32x4){0.f, 0.f, 0.f, 0.f};

    for (int kt = kbase; kt < kbase + Dim / KSPL; kt += 32) {
      __syncthreads();
      *(uint4*)&As[srow][scol] = *(const uint4*)&xaf[(size_t)(m0 + srow) * Dim + kt + scol];
      *(uint4*)&Bs[srow][scol] = *(const uint4*)&WgT[(size_t)srow * Dim + kt + scol];
      __syncthreads();
      half8 bfr = *(const half8*)&Bs[wv * 16 + mrow][quad * 8];
#pragma unroll
      for (int mi = 0; mi < 4; ++mi) {
        half8 afr = *(const half8*)&As[mi * 16 + mrow][quad * 8];
        acc[mi] = __builtin_amdgcn_mfma_f32_16x16x32_f16(afr, bfr, acc[mi], 0, 0, 0);
      }
    }

    int col = wv * 16 + mrow;          // only 0..23 real
    if (col < 24) {
#pragma unroll
      for (int mi = 0; mi < 4; ++mi) {
#pragma unroll
        for (int r2 = 0; r2 < 4; ++r2) {
          int row = m0 + mi * 16 + quad * 4 + r2;
          gpart[((size_t)ks * BN + row) * 32 + col] = acc[mi][r2];
        }
      }
    }
  }
}

// ---------------------------------------------------------------------------
// K2: final MFMA GEMM, 128M x 64N, epilogue dtype by flags.
// ---------------------------------------------------------------------------
__global__ __launch_bounds__(256) void k_gemm_fin(
    const _Float16* __restrict__ A, const _Float16* __restrict__ Bt,
    void* __restrict__ C, const int* __restrict__ flags, int Nn, int Kd)
{
  __shared__ __align__(16) _Float16 As[128][40];
  __shared__ __align__(16) _Float16 Bs[64][40];

  int tid = threadIdx.x, lane = tid & 63, wv = tid >> 6;
  int n0 = blockIdx.x * 64, m0 = blockIdx.y * 128;
  int mrow = lane & 15, quad = lane >> 4;
  int wm = wv * 32;
  int ar0 = tid >> 2, ac0 = (tid & 3) * 8;
  int ar1 = (tid + 256) >> 2;

  f32x4 acc[2][4];
#pragma unroll
  for (int mi = 0; mi < 2; ++mi)
#pragma unroll
    for (int ni = 0; ni < 4; ++ni) acc[mi][ni] = (f32x4){0.f, 0.f, 0.f, 0.f};

  for (int kt = 0; kt < Kd; kt += 32) {
    __syncthreads();
    *(uint4*)&As[ar0][ac0] = *(const uint4*)&A[(size_t)(m0 + ar0) * Kd + kt + ac0];
    *(uint4*)&As[ar1][ac0] = *(const uint4*)&A[(size_t)(m0 + ar1) * Kd + kt + ac0];
    *(uint4*)&Bs[ar0][ac0] = *(const uint4*)&Bt[(size_t)(n0 + ar0) * Kd + kt + ac0];
    __syncthreads();

    half8 bfr[4];
#pragma unroll
    for (int ni = 0; ni < 4; ++ni)
      bfr[ni] = *(const half8*)&Bs[ni * 16 + mrow][quad * 8];
#pragma unroll
    for (int mi = 0; mi < 2; ++mi) {
      half8 afr = *(const half8*)&As[wm + mi * 16 + mrow][quad * 8];
#pragma unroll
      for (int ni = 0; ni < 4; ++ni)
        acc[mi][ni] = __builtin_amdgcn_mfma_f32_16x16x32_f16(afr, bfr[ni], acc[mi][ni], 0, 0, 0);
    }
  }

  int any_bf16 = 0;
#pragma unroll
  for (int i2 = 0; i2 < 17; ++i2) any_bf16 |= (flags[i2] == 0);

#pragma unroll
  for (int mi = 0; mi < 2; ++mi) {
#pragma unroll
    for (int ni = 0; ni < 4; ++ni) {
      int col = n0 + ni * 16 + mrow;
#pragma unroll
      for (int r2 = 0; r2 < 4; ++r2) {
        int row = m0 + wm + mi * 16 + quad * 4 + r2;
        float v = acc[mi][ni][r2];
        size_t idx = (size_t)row * Nn + col;
        if (any_bf16) ((unsigned short*)C)[idx] = f2bf(v);
        else          ((float*)C)[idx] = v;
      }
    }
  }
}

// ---------------------------------------------------------------------------
// Gate preload helper: reduce KSPL partials + bias + sigmoid (96 threads)
// ---------------------------------------------------------------------------
DEV void load_gates(const float* __restrict__ gpart, const float* __restrict__ gbf,
                    int b, int h, int c, int tid,
                    float* gl, float* gd, float* gm)
{
  if (tid < 96) {
    int which = tid >> 5, t2 = tid & 31;
    int col = which * 8 + h;
    int row = b * Seq + c * CLEN + t2;
    float acc = gbf[col];
#pragma unroll
    for (int ks = 0; ks < KSPL; ++ks)
      acc += gpart[((size_t)ks * BN + row) * 32 + col];
    float sg = 1.f / (1.f + expf(-acc));
    if (which == 0) gl[t2] = sg; else if (which == 1) gd[t2] = sg; else gm[t2] = sg;
  }
}

// ---------------------------------------------------------------------------
// Phase A: per-chunk local scans -> chunk-END Z/S (f16) + scalars Mc,Dc,Wc
// ---------------------------------------------------------------------------
__global__ __launch_bounds__(256) void k_phaseA(
    const _Float16* __restrict__ kpre, const _Float16* __restrict__ vpre,
    const float* __restrict__ gkf,
    const float* __restrict__ gpart, const float* __restrict__ gbf,
    _Float16* __restrict__ ZS_Z, _Float16* __restrict__ ZS_S,
    float* __restrict__ Mc, float* __restrict__ Dc, float* __restrict__ Wc)
{
  int c = blockIdx.x, s = blockIdx.y;
  int b = s >> 3, h = s & 7;
  int tid = threadIdx.x, lane = tid & 63, wv = tid >> 6;
  int i = tid >> 2, j0 = (tid & 3) * 16;
  __shared__ float kn[CLEN][64], vv[CLEN][64];
  __shared__ float gl[CLEN], gd[CLEN], gm[CLEN];

  {
    int t = tid >> 3, col = (tid & 7) * 8;
    size_t g = ((size_t)(b * Seq + c * CLEN + t)) * Di + h * 64 + col;
    half8 kv = *(const half8*)&kpre[g];
    half8 vvv = *(const half8*)&vpre[g];
#pragma unroll
    for (int j = 0; j < 8; ++j) { kn[t][col + j] = (float)kv[j]; vv[t][col + j] = (float)vvv[j]; }
    load_gates(gpart, gbf, b, h, c, tid, gl, gd, gm);
  }
  __syncthreads();
  {
    float gk = gkf[h * 64 + lane];
#pragma unroll
    for (int tt = 0; tt < 8; ++tt) {
      int t = wv * 8 + tt;
      float kvv = kn[t][lane];
      float ss = kvv * kvv;
#pragma unroll
      for (int m = 1; m < 64; m <<= 1) ss += __shfl_xor(ss, m);
      kn[t][lane] = kvv * (1.f / fmaxf(sqrtf(ss) * 0.125f, 1e-8f)) * gk;
    }
  }
  __syncthreads();

  float Zl[16], Sl[16];
#pragma unroll
  for (int jj = 0; jj < 16; ++jj) { Zl[jj] = 0.f; Sl[jj] = 0.f; }
  float Mcum = 1.f, Dcum = 1.f, wacc = 0.f;

  for (int t = 0; t < CLEN; ++t) {
    float l = gl[t], dd = gd[t], mm = gm[t];
    float vi = vv[t][i];
    Mcum *= mm;
#pragma unroll
    for (int jj = 0; jj < 16; ++jj) {
      Zl[jj] = fmaf(mm, Zl[jj], -vi * kn[t][j0 + jj]);
      Sl[jj] = fmaf(dd, Sl[jj], -l * Zl[jj]);
    }
    wacc = fmaf(dd, wacc, -l * Mcum);
    Dcum *= dd;
  }
  size_t base = ((size_t)(s * CHUNK + c)) * 4096 + (size_t)i * 64 + j0;
  half8 zo0, zo1, so0, so1;
#pragma unroll
  for (int jj = 0; jj < 8; ++jj) {
    zo0[jj] = (_Float16)Zl[jj];     zo1[jj] = (_Float16)Zl[jj + 8];
    so0[jj] = (_Float16)Sl[jj];     so1[jj] = (_Float16)Sl[jj + 8];
  }
  *(half8*)&ZS_Z[base] = zo0; *(half8*)&ZS_Z[base + 8] = zo1;
  *(half8*)&ZS_S[base] = so0; *(half8*)&ZS_S[base + 8] = so1;
  if (tid == 0) {
    Mc[s * CHUNK + c] = Mcum; Dc[s * CHUNK + c] = Dcum; Wc[s * CHUNK + c] = wacc;
  }
}

// ---------------------------------------------------------------------------
// Phase C: self-carry (scans chunk-end records 0..c-1), then local scan + y.
// ---------------------------------------------------------------------------
__global__ __launch_bounds__(256) void k_phaseC(
    const _Float16* __restrict__ qpre, const _Float16* __restrict__ kpre,
    const _Float16* __restrict__ vpre,
    const float* __restrict__ gqf, const float* __restrict__ gkf,
    const float* __restrict__ gpart, const float* __restrict__ gbf,
    const _Float16* __restrict__ ZS_Z, const _Float16* __restrict__ ZS_S,
    const float* __restrict__ Mc, const float* __restrict__ Dc,
    const float* __restrict__ Wc,
    _Float16* __restrict__ yb)
{
  int c = blockIdx.x, s = blockIdx.y;
  int b = s >> 3, h = s & 7;
  int tid = threadIdx.x, lane = tid & 63, wv = tid >> 6;
  int i = tid >> 2, j0 = (tid & 3) * 16;
  __shared__ float kn[CLEN][64], vv[CLEN][64], qn[CLEN][64];
  __shared__ float gl[CLEN], gd[CLEN], gm[CLEN];

  // self-carry: chunk inputs from chunk-end records
  float Zi_[16], Si_[16], Zl[16], Sl[16];
#pragma unroll
  for (int jj = 0; jj < 16; ++jj) { Zi_[jj] = 0.f; Si_[jj] = 0.f; Zl[jj] = 0.f; Sl[jj] = 0.f; }
  for (int cc = 0; cc < c; ++cc) {
    size_t cb = ((size_t)(s * CHUNK + cc)) * 4096 + (size_t)i * 64 + j0;
    half8 z0 = *(const half8*)&ZS_Z[cb], z1 = *(const half8*)&ZS_Z[cb + 8];
    half8 s0 = *(const half8*)&ZS_S[cb], s1 = *(const half8*)&ZS_S[cb + 8];
    float mc = Mc[s * CHUNK + cc], dc = Dc[s * CHUNK + cc], wc = Wc[s * CHUNK + cc];
#pragma unroll
    for (int jj = 0; jj < 8; ++jj) {
      float zl0 = (float)z0[jj], sl0 = (float)s0[jj];
      float zl1 = (float)z1[jj], sl1 = (float)s1[jj];
      Si_[jj]     = fmaf(dc, Si_[jj],     fmaf(wc, Zi_[jj],     sl0));
      Zi_[jj]     = fmaf(mc, Zi_[jj],     zl0);
      Si_[jj + 8] = fmaf(dc, Si_[jj + 8], fmaf(wc, Zi_[jj + 8], sl1));
      Zi_[jj + 8] = fmaf(mc, Zi_[jj + 8], zl1);
    }
  }

  {
    int t = tid >> 3, col = (tid & 7) * 8;
    size_t g = ((size_t)(b * Seq + c * CLEN + t)) * Di + h * 64 + col;
    half8 kv = *(const half8*)&kpre[g];
    half8 vvv = *(const half8*)&vpre[g];
    half8 qv = *(const half8*)&qpre[g];
#pragma unroll
    for (int j = 0; j < 8; ++j) {
      kn[t][col + j] = (float)kv[j]; vv[t][col + j] = (float)vvv[j];
      qn[t][col + j] = (float)qv[j];
    }
    load_gates(gpart, gbf, b, h, c, tid, gl, gd, gm);
  }
  __syncthreads();
  {
    float gk = gkf[h * 64 + lane];
    float gq = gqf[h * 64 + lane];
#pragma unroll
    for (int tt = 0; tt < 8; ++tt) {
      int t = wv * 8 + tt;
      float kvv = kn[t][lane];
      float ssk = kvv * kvv;
      float qvv = qn[t][lane];
      float ssq = qvv * qvv;
#pragma unroll
      for (int m = 1; m < 64; m <<= 1) { ssk += __shfl_xor(ssk, m); ssq += __shfl_xor(ssq, m); }
      kn[t][lane] = kvv * (1.f / fmaxf(sqrtf(ssk) * 0.125f, 1e-8f)) * gk;
      qn[t][lane] = qvv * (1.f / fmaxf(sqrtf(ssq) * 0.125f, 1e-8f)) * gq;
    }
  }
  __syncthreads();

  float Mcum = 1.f, Dcum = 1.f, wacc = 0.f;
  float Dprev = 1.f, wprev = 0.f;

  for (int t = 0; t < CLEN; ++t) {
    float l = gl[t], dd = gd[t], mm = gm[t];

    float yp = 0.f;
#pragma unroll
    for (int jj = 0; jj < 16; ++jj) {
      float tmp = fmaf(Dprev, Si_[jj], fmaf(wprev, Zi_[jj], Sl[jj]));
      yp = fmaf(tmp, qn[t][j0 + jj], yp);
    }
    yp += __shfl_xor(yp, 1);
    yp += __shfl_xor(yp, 2);
    if ((tid & 3) == 0)
      yb[((size_t)(b * Seq + c * CLEN + t)) * Di + h * 64 + i] = (_Float16)yp;

    float vi = vv[t][i];
    Mcum *= mm;
#pragma unroll
    for (int jj = 0; jj < 16; ++jj) {
      Zl[jj] = fmaf(mm, Zl[jj], -vi * kn[t][j0 + jj]);
      Sl[jj] = fmaf(dd, Sl[jj], -l * Zl[jj]);
    }
    wacc = fmaf(dd, wacc, -l * Mcum);
    Dcum *= dd;
    Dprev = Dcum; wprev = wacc;
  }
}

// ---------------------------------------------------------------------------
extern "C" void kernel_launch(void* const* d_in, const int* in_sizes, int n_in,
                              void* d_out, int out_size, void* d_ws, size_t ws_size,
                              hipStream_t stream) {
  InPtrs ip;
  for (int i = 0; i < 17; ++i) { ip.p[i] = d_in[i]; ip.n[i] = in_sizes[i]; }

  char* p = (char*)d_ws;
  auto take = [&](size_t bytes) -> char* {
    char* q = p; p += (bytes + 255) & ~(size_t)255; return q;
  };
  int* flags           = (int*)take(32 * 4);
  _Float16* xaf        = (_Float16*)take((size_t)BN * Dim * 2);   // 4 MB
  _Float16* qc         = (_Float16*)take((size_t)BN * Dim * 2);   // 4 MB
  _Float16* kc         = (_Float16*)take((size_t)BN * Dim * 2);   // 4 MB
  _Float16* vc         = (_Float16*)take((size_t)BN * Dim * 2);   // 4 MB
  _Float16* qpre       = (_Float16*)take((size_t)BN * Di * 2);    // 2 MB
  _Float16* kpre       = (_Float16*)take((size_t)BN * Di * 2);    // 2 MB
  _Float16* vpre       = (_Float16*)take((size_t)BN * Di * 2);    // 2 MB
  float* gpart         = (float*)take((size_t)KSPL * BN * 32 * 4); // 2 MB
  float* Mc            = (float*)take((size_t)NSEQ * CHUNK * 4);
  float* Dc            = (float*)take((size_t)NSEQ * CHUNK * 4);
  float* Wc            = (float*)take((size_t)NSEQ * CHUNK * 4);
  _Float16* wqT        = (_Float16*)take((size_t)Di * Dim * 2);   // 1 MB
  _Float16* wkT        = (_Float16*)take((size_t)Di * Dim * 2);   // 1 MB
  _Float16* wvT        = (_Float16*)take((size_t)Di * Dim * 2);   // 1 MB
  _Float16* woT        = (_Float16*)take((size_t)Dim * Di * 2);   // 1 MB
  _Float16* WgT        = (_Float16*)take((size_t)64 * Dim * 2);   // 128 KB
  float* gqf           = (float*)take(Di * 4);
  float* gkf           = (float*)take(Di * 4);
  float* gbf           = (float*)take(32 * 4);
  // Aliases: qc/kc/vc are dead after k_mid
  _Float16* ZS_Z       = qc;
  _Float16* ZS_S       = kc;
  _Float16* yb         = vc;

  k_prep_rmsconv<<<1345, 256, 0, stream>>>(ip, flags, wqT, wkT, wvT, woT, WgT,
                                           gqf, gkf, gbf, xaf, qc, kc, vc);

  k_mid<<<640, 256, 0, stream>>>(qc, kc, vc, wqT, wkT, wvT, xaf, WgT,
                                 qpre, kpre, vpre, gpart);

  k_phaseA<<<dim3(CHUNK, NSEQ), 256, 0, stream>>>(kpre, vpre, gkf,
                                                  gpart, gbf,
                                                  ZS_Z, ZS_S, Mc, Dc, Wc);
  k_phaseC<<<dim3(CHUNK, NSEQ), 256, 0, stream>>>(qpre, kpre, vpre, gqf, gkf,
                                                  gpart, gbf,
                                                  ZS_Z, ZS_S, Mc, Dc, Wc, yb);

  k_gemm_fin<<<dim3(Dim / 64, BN / 128), 256, 0, stream>>>(
      yb, woT, d_out, flags, Dim, Di);
}